// Round 1
// baseline (149.980 us; speedup 1.0000x reference)
//
#include <hip/hip_runtime.h>

// Problem constants (B,R,C = 32, NB=2, NC=20)
#define Bdim 32
#define Rdim 32
#define Cdim 32
#define NBOX 2
#define NCLS 20
#define CH   174   // 6 + 2*(R+C) + 2*NC
#define CHP  348   // NB * CH
#define BASE 134   // 6 + 2*(R+C)

// One wave (64 lanes) per cell. Wave-uniform flag branch; ballot argmax of the
// exact one-hot row/col pointers; redundant per-lane scalar score math (all
// loads broadcast); lane-parallel coalesced 1.0f stores for the mask spans.
__global__ __launch_bounds__(256) void convbox_match_kernel(
    const float* __restrict__ pred, const float* __restrict__ label,
    float* __restrict__ out0,   // pred_mask  [B,R,C,CHP]
    float* __restrict__ out1,   // label_mask [B,R,C,CH]
    float* __restrict__ out2)   // label_mask copy
{
    const int wave = (blockIdx.x << 2) | (threadIdx.x >> 6);   // cell index
    const int lane = threadIdx.x & 63;
    const int c = wave & 31;
    const int r = (wave >> 5) & 31;
    const int b = wave >> 10;

    const float* Lcell = label + (size_t)wave * CH;

    // flag: exact == 1.0 test (wave-uniform)
    if (Lcell[0] != 1.0f) return;

    // argmax of one-hot via ballot (first set bit == first max index)
    float vr = (lane < 32) ? Lcell[6 + lane] : 0.0f;
    float vc = (lane < 32) ? Lcell[6 + 32 + lane] : 0.0f;
    unsigned long long mr = __ballot(lane < 32 && vr == 1.0f);
    unsigned long long mc = __ballot(lane < 32 && vc == 1.0f);
    const int rowc = mr ? (int)__builtin_ctzll(mr) : 0;
    const int colc = mc ? (int)__builtin_ctzll(mc) : 0;

    const int cornIdx = (b * Rdim + rowc) * Cdim + colc;
    const float* Lcorn = label + (size_t)cornIdx * CH;
    const float* Pcell = pred + (size_t)wave * CHP;
    const float* Pcorn = pred + (size_t)cornIdx * CHP;

    // ground-truth box (division by 32 == exact *0.03125)
    const float inv = 0.03125f;
    float xm_t = (Lcell[2] + (float)c) * inv;
    float ym_t = (Lcell[3] + (float)r) * inv;
    float xc_t = (Lcorn[4] + (float)colc) * inv;
    float yc_t = (Lcorn[5] + (float)rowc) * inv;
    float tw = fabsf(xm_t - xc_t) * 2.0f;
    float th = fabsf(ym_t - yc_t) * 2.0f;

    float score[NBOX];
#pragma unroll
    for (int i = 0; i < NBOX; ++i) {
        float cat = 0.0f;
#pragma unroll
        for (int k = 0; k < NCLS; ++k) {
            float d1 = Pcell[268 + i * NCLS + k] - Lcell[BASE + k];
            float d2 = Pcorn[308 + i * NCLS + k] - Lcorn[BASE + NCLS + k];
            cat += d1 * d1 + d2 * d2;
        }
        float conn_m = Pcell[12 + i * 64 + rowc] * Pcell[12 + i * 64 + 32 + colc];
        float conn_c = Pcorn[140 + i * 64 + r]   * Pcorn[140 + i * 64 + 32 + c];
        float conn = (conn_m + conn_c) * 0.5f;
        // faithful-to-source channel offsets by col/row
        float xm_p = Pcell[(NBOX + i) * 2 + 0 + c] * inv;
        float ym_p = Pcell[(NBOX + i) * 2 + 1 + r] * inv;
        float xc_p = Pcorn[(NBOX * 2 + i) * 2 + 0 + colc] * inv;
        float yc_p = Pcorn[(NBOX * 2 + i) * 2 + 1 + rowc] * inv;
        float ow = fabsf(xm_p - xc_p) * 2.0f;
        float oh = fabsf(ym_p - yc_p) * 2.0f;
        float w = fminf(xm_p + ow * 0.5f, xm_t + tw * 0.5f)
                - fmaxf(xm_p - ow * 0.5f, xm_t - tw * 0.5f);
        float h = fminf(ym_p + oh * 0.5f, ym_t + th * 0.5f)
                - fmaxf(ym_p - oh * 0.5f, ym_t - th * 0.5f);
        float inter = (w < 0.0f || h < 0.0f) ? 0.0f : w * h;
        float uni = ow * oh + tw * th - inter;
        float iou = inter / uni;
        float rmse = (xm_p - xm_t) * (xm_p - xm_t) + (ym_p - ym_t) * (ym_p - ym_t)
                   + (ow - tw) * (ow - tw) + (oh - th) * (oh - th);
        score[i] = conn * (iou - rmse + 0.1f) + 0.1f * (2.0f - cat);
    }
    const int best = (score[1] > score[0]) ? 1 : 0;

    // scatter 1.0f at flagged cells (races write identical value -> benign)
#pragma unroll
    for (int n = 0; n < 2; ++n) {
        const int rt = n ? rowc : r;
        const int ct = n ? colc : c;
        const int tcell = (b * Rdim + rt) * Cdim + ct;

        float* pm = out0 + (size_t)tcell * CHP;
        if (lane == 0) pm[n * NBOX + best] = 1.0f;
        if (lane < 2)  pm[(1 + n) * NBOX * 2 + 2 * best + lane] = 1.0f;
        pm[(6 + n * 64) * NBOX + 64 * best + lane] = 1.0f;           // 64 lanes
        if (lane < NCLS) pm[(BASE + n * NCLS) * NBOX + NCLS * best + lane] = 1.0f;

        float* l1 = out1 + (size_t)tcell * CH;
        float* l2 = out2 + (size_t)tcell * CH;
        if (lane == 0) { l1[n] = 1.0f; l2[n] = 1.0f; }
        if (lane < 2)  { l1[2 * (1 + n) + lane] = 1.0f; l2[2 * (1 + n) + lane] = 1.0f; }
        l1[6 + n * 64 + lane] = 1.0f;                                 // 64 lanes
        l2[6 + n * 64 + lane] = 1.0f;
        if (lane < NCLS) { l1[BASE + n * NCLS + lane] = 1.0f; l2[BASE + n * NCLS + lane] = 1.0f; }
    }
}

extern "C" void kernel_launch(void* const* d_in, const int* in_sizes, int n_in,
                              void* d_out, int out_size, void* d_ws, size_t ws_size,
                              hipStream_t stream) {
    const float* pred  = (const float*)d_in[0];
    const float* label = (const float*)d_in[1];
    // d_in[2]/d_in[3] = num_box/num_class, hard-coded as NBOX/NCLS

    float* out0 = (float*)d_out;                                   // pred_mask
    float* out1 = out0 + (size_t)Bdim * Rdim * Cdim * CHP;         // label_mask
    float* out2 = out1 + (size_t)Bdim * Rdim * Cdim * CH;          // label_mask copy

    // zero the whole output (poisoned to 0xAA before each timed call)
    hipMemsetAsync(d_out, 0, (size_t)out_size * sizeof(float), stream);

    const int n_cells = Bdim * Rdim * Cdim;        // 32768 cells, 1 wave each
    const int blocks = n_cells / 4;                // 4 waves per 256-thread block
    convbox_match_kernel<<<blocks, 256, 0, stream>>>(pred, label, out0, out1, out2);
}